// Round 6
// baseline (358.117 us; speedup 1.0000x reference)
//
#include <hip/hip_runtime.h>

#define B_SZ 8
#define N_SZ 65536
#define C_SZ 128
#define K_SZ 15
#define THREADS 256
#define WAVES 4
#define ROWS 4            // c-rows per wave (acc = ROWS*K_SZ = 60 VGPRs)
#define C_BLK 16          // c-rows per block (WAVES*ROWS)
#define G 8               // c-groups (C_SZ / C_BLK)
#define W_STEP 256        // n per step (64 lanes x float4)
#define S_SPANS 32        // n-spans per batch
#define NSPAN 2048        // N_SZ / S_SPANS
#define STEPS 8           // NSPAN / W_STEP
#define PART_PER_BLK (C_BLK * K_SZ)   // 240
#define INV_KP_EXTENT (1.0f / 0.48f)

// Block = (b, cg, s): 16 c-rows over an n-span of 2048. Every x wave-load is a
// contiguous 1KB segment (lane*16B) -> streaming-friendly. Weight table
// w[k][256] recomputed per block (x8 redundant, cheap) into double-buffered
// LDS. 2-deep register prefetch on x (xA/xB). ROWS=4 keeps VGPR < 128: the
// round-5 ROWS=8 variant spilled (WRITE_SIZE 186 MB of scratch traffic).

__global__ __launch_bounds__(THREADS, 4) void kpconv_main(
    const float* __restrict__ p, const float* __restrict__ x,
    const float* __restrict__ kp, float* __restrict__ part) {
  __shared__ float wt[2][K_SZ][W_STEP];   // 30 KB
  __shared__ float kps[K_SZ * 3];

  const int tid = threadIdx.x;
  const int blk = blockIdx.x;               // ((b*G)+cg)*S_SPANS + s
  const int b  = blk / (G * S_SPANS);
  const int cg = (blk / S_SPANS) % G;
  const int s  = blk % S_SPANS;
  const int nbase = s * NSPAN;

  if (tid < K_SZ * 3) kps[tid] = kp[tid];

  const int lane = tid & 63;
  const int wid  = __builtin_amdgcn_readfirstlane(tid >> 6);

  const float* pb = p + (size_t)b * N_SZ * 3 + (size_t)nbase * 3;
  const float* xrow0 = x + (size_t)b * C_SZ * N_SZ
                         + (size_t)(cg * C_BLK + wid * ROWS) * N_SZ + nbase;

  float acc[ROWS][K_SZ];
#pragma unroll
  for (int r = 0; r < ROWS; ++r)
#pragma unroll
    for (int k = 0; k < K_SZ; ++k) acc[r][k] = 0.0f;

#define LOAD_X(dst, toff)                                                     \
  do {                                                                        \
    _Pragma("unroll")                                                         \
    for (int r_ = 0; r_ < ROWS; ++r_)                                         \
      dst[r_] = *reinterpret_cast<const float4*>(                             \
          xrow0 + (size_t)r_ * N_SZ + (toff) * W_STEP + 4 * lane);            \
  } while (0)

#define FILL_WT(bufi, toff)                                                   \
  do {                                                                        \
    const int nl_ = (toff) * W_STEP + tid;                                    \
    const float px_ = pb[3 * nl_ + 0];                                        \
    const float py_ = pb[3 * nl_ + 1];                                        \
    const float pz_ = pb[3 * nl_ + 2];                                        \
    _Pragma("unroll")                                                         \
    for (int k_ = 0; k_ < K_SZ; ++k_) {                                       \
      const float dx_ = px_ - kps[3 * k_ + 0];                                \
      const float dy_ = py_ - kps[3 * k_ + 1];                                \
      const float dz_ = pz_ - kps[3 * k_ + 2];                                \
      const float d_ = sqrtf(fmaf(dx_, dx_, fmaf(dy_, dy_, dz_ * dz_)));      \
      wt[bufi][k_][tid] = fmaxf(1.0f - d_ * INV_KP_EXTENT, 0.0f);             \
    }                                                                         \
  } while (0)

#define DO_FMA(xr, bufi)                                                      \
  do {                                                                        \
    _Pragma("unroll")                                                         \
    for (int k_ = 0; k_ < K_SZ; ++k_) {                                       \
      const float4 wq_ = *reinterpret_cast<const float4*>(&wt[bufi][k_][4 * lane]); \
      _Pragma("unroll")                                                       \
      for (int r_ = 0; r_ < ROWS; ++r_)                                       \
        acc[r_][k_] = fmaf(wq_.x, xr[r_].x,                                   \
                      fmaf(wq_.y, xr[r_].y,                                   \
                      fmaf(wq_.z, xr[r_].z,                                   \
                      fmaf(wq_.w, xr[r_].w, acc[r_][k_]))));                  \
    }                                                                         \
  } while (0)

  float4 xA[ROWS], xB[ROWS];
  __syncthreads();          // kps visible
  FILL_WT(0, 0);
  LOAD_X(xA, 0);
  __syncthreads();          // wt[0] ready

  for (int t = 0; t < STEPS; t += 2) {
    if (t + 1 < STEPS) {
      LOAD_X(xB, t + 1);
      FILL_WT(1, t + 1);
    }
    DO_FMA(xA, 0);
    __syncthreads();
    if (t + 1 < STEPS) {
      if (t + 2 < STEPS) {
        LOAD_X(xA, t + 2);
        FILL_WT(0, t + 2);
      }
      DO_FMA(xB, 1);
      __syncthreads();
    }
  }

  // epilogue: reduce acc[r][k] across the 64 lanes (n-dimension);
  // lane k keeps value k of row r, lanes 0..14 store coalesced.
  float* pout = part + (size_t)blk * PART_PER_BLK + wid * (ROWS * K_SZ);
#pragma unroll
  for (int r = 0; r < ROWS; ++r) {
    float keep = 0.0f;
#pragma unroll
    for (int k = 0; k < K_SZ; ++k) {
      float v = acc[r][k];
      v += __shfl_xor(v, 1);
      v += __shfl_xor(v, 2);
      v += __shfl_xor(v, 4);
      v += __shfl_xor(v, 8);
      v += __shfl_xor(v, 16);
      v += __shfl_xor(v, 32);
      if (lane == k) keep = v;
    }
    if (lane < K_SZ) pout[r * K_SZ + lane] = keep;
  }
}

// part[blk][wid][r][k], blk = (b*G+cg)*S_SPANS + s, c = cg*16 + wid*4 + r.
__global__ __launch_bounds__(C_SZ) void kpconv_reduce_gemm(
    const float* __restrict__ part, const float* __restrict__ W,
    float* __restrict__ out) {
  const int k = blockIdx.x;   // 0..14
  const int b = blockIdx.y;   // 0..7
  const int tid = threadIdx.x;  // c
  __shared__ float row[C_SZ];

  const int cg = tid >> 4, wid = (tid >> 2) & 3, r = tid & 3;
  const size_t base = ((size_t)(b * G + cg) * S_SPANS) * PART_PER_BLK
                    + wid * (ROWS * K_SZ) + r * K_SZ + k;
  float sum = 0.0f;
  for (int ss = 0; ss < S_SPANS; ++ss)
    sum += part[base + (size_t)ss * PART_PER_BLK];
  row[tid] = sum;
  __syncthreads();

  float acc = 0.0f;
  const float* Wk = W + (size_t)k * C_SZ * C_SZ;
#pragma unroll 8
  for (int c = 0; c < C_SZ; ++c) acc += row[c] * Wk[(size_t)c * C_SZ + tid];
  atomicAdd(&out[b * C_SZ + tid], acc);
}

extern "C" void kernel_launch(void* const* d_in, const int* in_sizes, int n_in,
                              void* d_out, int out_size, void* d_ws, size_t ws_size,
                              hipStream_t stream) {
  const float* p  = (const float*)d_in[0];
  const float* x  = (const float*)d_in[1];
  const float* w  = (const float*)d_in[2];
  const float* kp = (const float*)d_in[3];
  float* out  = (float*)d_out;
  float* part = (float*)d_ws;  // needs 2048 * 240 * 4B = ~2 MB

  hipMemsetAsync(d_out, 0, (size_t)out_size * sizeof(float), stream);
  kpconv_main<<<dim3(B_SZ * G * S_SPANS), THREADS, 0, stream>>>(p, x, kp, part);
  kpconv_reduce_gemm<<<dim3(K_SZ, B_SZ), C_SZ, 0, stream>>>(part, w, out);
}

// Round 7
// 125.515 us; speedup vs baseline: 2.8532x; 2.8532x over previous
//
#include <hip/hip_runtime.h>

#define B_SZ 8
#define N_SZ 65536
#define C_SZ 128
#define K_SZ 15
#define THREADS 256
#define WAVES 4
#define ROWS 4            // c-rows per wave (acc = ROWS*K_SZ = 60 VGPRs)
#define C_BLK 16          // c-rows per block (WAVES*ROWS)
#define G 8               // c-groups (C_SZ / C_BLK)
#define W_STEP 256        // n per step (64 lanes x float4)
#define S_SPANS 32        // n-spans per batch
#define NSPAN 2048        // N_SZ / S_SPANS
#define STEPS 8           // NSPAN / W_STEP
#define PART_PER_BLK (C_BLK * K_SZ)   // 240
#define INV_KP_EXTENT (1.0f / 0.48f)

// Block = (b, cg, s): 16 c-rows over an n-span of 2048. Every x wave-load is a
// contiguous 1KB segment (lane*16B) -> streaming-friendly. Weight table
// w[k][256] recomputed per block (x8 redundant, cheap) into double-buffered
// LDS. 2-deep register prefetch on x (xA/xB).
// Register history: ROWS=8 @cap128 spilled (r5, WRITE 186MB); ROWS=4 @cap64
// spilled (r6, launch_bounds(,4) -> 64 VGPR, WRITE 815MB). This round:
// ROWS=4 demand ~112 with launch_bounds(,2) -> cap 128, zero spill expected.

__global__ __launch_bounds__(THREADS, 2) void kpconv_main(
    const float* __restrict__ p, const float* __restrict__ x,
    const float* __restrict__ kp, float* __restrict__ part) {
  __shared__ float wt[2][K_SZ][W_STEP];   // 30 KB
  __shared__ float kps[K_SZ * 3];

  const int tid = threadIdx.x;
  const int blk = blockIdx.x;               // ((b*G)+cg)*S_SPANS + s
  const int b  = blk / (G * S_SPANS);
  const int cg = (blk / S_SPANS) % G;
  const int s  = blk % S_SPANS;
  const int nbase = s * NSPAN;

  if (tid < K_SZ * 3) kps[tid] = kp[tid];

  const int lane = tid & 63;
  const int wid  = __builtin_amdgcn_readfirstlane(tid >> 6);

  const float* pb = p + (size_t)b * N_SZ * 3 + (size_t)nbase * 3;
  const float* xrow0 = x + (size_t)b * C_SZ * N_SZ
                         + (size_t)(cg * C_BLK + wid * ROWS) * N_SZ + nbase;

  float acc[ROWS][K_SZ];
#pragma unroll
  for (int r = 0; r < ROWS; ++r)
#pragma unroll
    for (int k = 0; k < K_SZ; ++k) acc[r][k] = 0.0f;

#define LOAD_X(dst, toff)                                                     \
  do {                                                                        \
    _Pragma("unroll")                                                         \
    for (int r_ = 0; r_ < ROWS; ++r_)                                         \
      dst[r_] = *reinterpret_cast<const float4*>(                             \
          xrow0 + (size_t)r_ * N_SZ + (toff) * W_STEP + 4 * lane);            \
  } while (0)

#define FILL_WT(bufi, toff)                                                   \
  do {                                                                        \
    const int nl_ = (toff) * W_STEP + tid;                                    \
    const float px_ = pb[3 * nl_ + 0];                                        \
    const float py_ = pb[3 * nl_ + 1];                                        \
    const float pz_ = pb[3 * nl_ + 2];                                        \
    _Pragma("unroll")                                                         \
    for (int k_ = 0; k_ < K_SZ; ++k_) {                                       \
      const float dx_ = px_ - kps[3 * k_ + 0];                                \
      const float dy_ = py_ - kps[3 * k_ + 1];                                \
      const float dz_ = pz_ - kps[3 * k_ + 2];                                \
      const float d_ = sqrtf(fmaf(dx_, dx_, fmaf(dy_, dy_, dz_ * dz_)));      \
      wt[bufi][k_][tid] = fmaxf(1.0f - d_ * INV_KP_EXTENT, 0.0f);             \
    }                                                                         \
  } while (0)

#define DO_FMA(xr, bufi)                                                      \
  do {                                                                        \
    _Pragma("unroll")                                                         \
    for (int k_ = 0; k_ < K_SZ; ++k_) {                                       \
      const float4 wq_ = *reinterpret_cast<const float4*>(&wt[bufi][k_][4 * lane]); \
      _Pragma("unroll")                                                       \
      for (int r_ = 0; r_ < ROWS; ++r_)                                       \
        acc[r_][k_] = fmaf(wq_.x, xr[r_].x,                                   \
                      fmaf(wq_.y, xr[r_].y,                                   \
                      fmaf(wq_.z, xr[r_].z,                                   \
                      fmaf(wq_.w, xr[r_].w, acc[r_][k_]))));                  \
    }                                                                         \
  } while (0)

  float4 xA[ROWS], xB[ROWS];
  __syncthreads();          // kps visible
  FILL_WT(0, 0);
  LOAD_X(xA, 0);
  __syncthreads();          // wt[0] ready

  for (int t = 0; t < STEPS; t += 2) {
    if (t + 1 < STEPS) {
      LOAD_X(xB, t + 1);
      FILL_WT(1, t + 1);
    }
    DO_FMA(xA, 0);
    __syncthreads();
    if (t + 1 < STEPS) {
      if (t + 2 < STEPS) {
        LOAD_X(xA, t + 2);
        FILL_WT(0, t + 2);
      }
      DO_FMA(xB, 1);
      __syncthreads();
    }
  }

  // epilogue: reduce acc[r][k] across the 64 lanes (n-dimension);
  // lane k keeps value k of row r, lanes 0..14 store coalesced.
  float* pout = part + (size_t)blk * PART_PER_BLK + wid * (ROWS * K_SZ);
#pragma unroll
  for (int r = 0; r < ROWS; ++r) {
    float keep = 0.0f;
#pragma unroll
    for (int k = 0; k < K_SZ; ++k) {
      float v = acc[r][k];
      v += __shfl_xor(v, 1);
      v += __shfl_xor(v, 2);
      v += __shfl_xor(v, 4);
      v += __shfl_xor(v, 8);
      v += __shfl_xor(v, 16);
      v += __shfl_xor(v, 32);
      if (lane == k) keep = v;
    }
    if (lane < K_SZ) pout[r * K_SZ + lane] = keep;
  }
}

// part[blk][wid][r][k], blk = (b*G+cg)*S_SPANS + s, c = cg*16 + wid*4 + r.
__global__ __launch_bounds__(C_SZ) void kpconv_reduce_gemm(
    const float* __restrict__ part, const float* __restrict__ W,
    float* __restrict__ out) {
  const int k = blockIdx.x;   // 0..14
  const int b = blockIdx.y;   // 0..7
  const int tid = threadIdx.x;  // c
  __shared__ float row[C_SZ];

  const int cg = tid >> 4, wid = (tid >> 2) & 3, r = tid & 3;
  const size_t base = ((size_t)(b * G + cg) * S_SPANS) * PART_PER_BLK
                    + wid * (ROWS * K_SZ) + r * K_SZ + k;
  float sum = 0.0f;
  for (int ss = 0; ss < S_SPANS; ++ss)
    sum += part[base + (size_t)ss * PART_PER_BLK];
  row[tid] = sum;
  __syncthreads();

  float acc = 0.0f;
  const float* Wk = W + (size_t)k * C_SZ * C_SZ;
#pragma unroll 8
  for (int c = 0; c < C_SZ; ++c) acc += row[c] * Wk[(size_t)c * C_SZ + tid];
  atomicAdd(&out[b * C_SZ + tid], acc);
}

extern "C" void kernel_launch(void* const* d_in, const int* in_sizes, int n_in,
                              void* d_out, int out_size, void* d_ws, size_t ws_size,
                              hipStream_t stream) {
  const float* p  = (const float*)d_in[0];
  const float* x  = (const float*)d_in[1];
  const float* w  = (const float*)d_in[2];
  const float* kp = (const float*)d_in[3];
  float* out  = (float*)d_out;
  float* part = (float*)d_ws;  // needs 2048 * 240 * 4B = ~2 MB

  hipMemsetAsync(d_out, 0, (size_t)out_size * sizeof(float), stream);
  kpconv_main<<<dim3(B_SZ * G * S_SPANS), THREADS, 0, stream>>>(p, x, kp, part);
  kpconv_reduce_gemm<<<dim3(K_SZ, B_SZ), C_SZ, 0, stream>>>(part, w, out);
}

// Round 9
// 112.821 us; speedup vs baseline: 3.1742x; 1.1125x over previous
//
#include <hip/hip_runtime.h>

#define B_SZ 8
#define N_SZ 65536
#define C_SZ 128
#define K_SZ 15
#define KPAD 16
#define THREADS 256
#define WAVES 4
#define ROWS 4            // c-rows per wave (acc = ROWS*K_SZ = 60 VGPRs)
#define C_BLK 16          // c-rows per block
#define G 8               // c-groups (C_SZ / C_BLK)
#define NTILE 256         // n per step (64 lanes x float4)
#define TILES (N_SZ / NTILE)          // 256 tiles per batch
#define S_SPANS 32        // n-spans per batch
#define NSPAN 2048
#define STEPS (NSPAN / NTILE)         // 8
#define PART_PER_BLK (C_BLK * K_SZ)   // 240
#define NBLKS (B_SZ * G * S_SPANS)    // 2048
#define INV_KP_EXTENT (1.0f / 0.48f)

// ---------- pre-pass: w[b][tile][k(padded 16)][n%256], contiguous 16KB/tile ----
__global__ __launch_bounds__(THREADS) void kpconv_weights(
    const float* __restrict__ p, const float* __restrict__ kp,
    float* __restrict__ wglob) {
  __shared__ float kps[K_SZ * 3];
  const int tid = threadIdx.x;
  if (tid < K_SZ * 3) kps[tid] = kp[tid];
  __syncthreads();

  const int b    = blockIdx.x / TILES;
  const int tile = blockIdx.x % TILES;
  const int n    = tile * NTILE + tid;
  const float* pp = p + ((size_t)b * N_SZ + n) * 3;
  const float px = pp[0], py = pp[1], pz = pp[2];
  float* wout = wglob + ((size_t)b * TILES + tile) * (KPAD * NTILE);
#pragma unroll
  for (int k = 0; k < K_SZ; ++k) {
    const float dx = px - kps[3 * k + 0];
    const float dy = py - kps[3 * k + 1];
    const float dz = pz - kps[3 * k + 2];
    const float d = sqrtf(fmaf(dx, dx, fmaf(dy, dy, dz * dz)));
    wout[k * NTILE + tid] = fmaxf(1.0f - d * INV_KP_EXTENT, 0.0f);
  }
  wout[15 * NTILE + tid] = 0.0f;  // pad row
}

// ---------- main: stream x, stage 16KB w-tile into dbuf LDS, 240 FMA/thr/step --
__global__ __launch_bounds__(THREADS, 2) void kpconv_main_pw(
    const float* __restrict__ x, const float* __restrict__ wglob,
    float* __restrict__ part) {
  __shared__ float wt[2][KPAD * NTILE];   // 32 KB

  const int tid = threadIdx.x;
  const int blk = blockIdx.x;               // ((b*G)+cg)*S_SPANS + s
  const int b  = blk / (G * S_SPANS);
  const int cg = (blk / S_SPANS) % G;
  const int s  = blk % S_SPANS;

  const int lane = tid & 63;
  const int wid  = __builtin_amdgcn_readfirstlane(tid >> 6);

  const float* xrow0 = x + (size_t)b * C_SZ * N_SZ
                         + (size_t)(cg * C_BLK + wid * ROWS) * N_SZ + s * NSPAN;
  const float4* wsrc = (const float4*)(wglob
                         + ((size_t)b * TILES + s * STEPS) * (KPAD * NTILE));

  float acc[ROWS][K_SZ];
#pragma unroll
  for (int r = 0; r < ROWS; ++r)
#pragma unroll
    for (int k = 0; k < K_SZ; ++k) acc[r][k] = 0.0f;

#define LOAD_X(dst, toff)                                                     \
  do {                                                                        \
    _Pragma("unroll")                                                         \
    for (int r_ = 0; r_ < ROWS; ++r_)                                         \
      dst[r_] = *reinterpret_cast<const float4*>(                             \
          xrow0 + (size_t)r_ * N_SZ + (toff) * NTILE + 4 * lane);             \
  } while (0)

#define STAGE_WT(bufi, toff)                                                  \
  do {                                                                        \
    const float4* s_ = wsrc + (size_t)(toff) * (KPAD * NTILE / 4);            \
    const float4 v0_ = s_[tid];                                               \
    const float4 v1_ = s_[tid + 256];                                         \
    const float4 v2_ = s_[tid + 512];                                         \
    const float4 v3_ = s_[tid + 768];                                         \
    float4* d_ = reinterpret_cast<float4*>(&wt[bufi][0]);                     \
    d_[tid] = v0_;                                                            \
    d_[tid + 256] = v1_;                                                      \
    d_[tid + 512] = v2_;                                                      \
    d_[tid + 768] = v3_;                                                      \
  } while (0)

#define DO_FMA(xr, bufi)                                                      \
  do {                                                                        \
    _Pragma("unroll")                                                         \
    for (int k_ = 0; k_ < K_SZ; ++k_) {                                       \
      const float4 wq_ = *reinterpret_cast<const float4*>(                    \
          &wt[bufi][k_ * NTILE + 4 * lane]);                                  \
      _Pragma("unroll")                                                       \
      for (int r_ = 0; r_ < ROWS; ++r_)                                       \
        acc[r_][k_] = fmaf(wq_.x, xr[r_].x,                                   \
                      fmaf(wq_.y, xr[r_].y,                                   \
                      fmaf(wq_.z, xr[r_].z,                                   \
                      fmaf(wq_.w, xr[r_].w, acc[r_][k_]))));                  \
    }                                                                         \
  } while (0)

  float4 xA[ROWS], xB[ROWS];
  STAGE_WT(0, 0);
  LOAD_X(xA, 0);
  __syncthreads();          // wt[0] ready

  for (int t = 0; t < STEPS; t += 2) {
    if (t + 1 < STEPS) {
      LOAD_X(xB, t + 1);
      STAGE_WT(1, t + 1);
    }
    DO_FMA(xA, 0);
    __syncthreads();
    if (t + 1 < STEPS) {
      if (t + 2 < STEPS) {
        LOAD_X(xA, t + 2);
        STAGE_WT(0, t + 2);
      }
      DO_FMA(xB, 1);
      __syncthreads();
    }
  }

  // epilogue: reduce acc[r][k] across 64 lanes; lane k keeps k; lanes 0..14 store.
  float* pout = part + (size_t)blk * PART_PER_BLK + wid * (ROWS * K_SZ);
#pragma unroll
  for (int r = 0; r < ROWS; ++r) {
    float keep = 0.0f;
#pragma unroll
    for (int k = 0; k < K_SZ; ++k) {
      float v = acc[r][k];
      v += __shfl_xor(v, 1);
      v += __shfl_xor(v, 2);
      v += __shfl_xor(v, 4);
      v += __shfl_xor(v, 8);
      v += __shfl_xor(v, 16);
      v += __shfl_xor(v, 32);
      if (lane == k) keep = v;
    }
    if (lane < K_SZ) pout[r * K_SZ + lane] = keep;
  }
}

// ---------- fallback main (round-7 structure, in-loop weight compute) ---------
__global__ __launch_bounds__(THREADS, 2) void kpconv_main_fb(
    const float* __restrict__ p, const float* __restrict__ x,
    const float* __restrict__ kp, float* __restrict__ part) {
  __shared__ float wt[2][K_SZ][NTILE];
  __shared__ float kps[K_SZ * 3];

  const int tid = threadIdx.x;
  const int blk = blockIdx.x;
  const int b  = blk / (G * S_SPANS);
  const int cg = (blk / S_SPANS) % G;
  const int s  = blk % S_SPANS;
  const int nbase = s * NSPAN;

  if (tid < K_SZ * 3) kps[tid] = kp[tid];

  const int lane = tid & 63;
  const int wid  = __builtin_amdgcn_readfirstlane(tid >> 6);

  const float* pb = p + (size_t)b * N_SZ * 3 + (size_t)nbase * 3;
  const float* xrow0 = x + (size_t)b * C_SZ * N_SZ
                         + (size_t)(cg * C_BLK + wid * ROWS) * N_SZ + nbase;

  float acc[ROWS][K_SZ];
#pragma unroll
  for (int r = 0; r < ROWS; ++r)
#pragma unroll
    for (int k = 0; k < K_SZ; ++k) acc[r][k] = 0.0f;

#define FILL_WT(bufi, toff)                                                   \
  do {                                                                        \
    const int nl_ = (toff) * NTILE + tid;                                     \
    const float px_ = pb[3 * nl_ + 0];                                        \
    const float py_ = pb[3 * nl_ + 1];                                        \
    const float pz_ = pb[3 * nl_ + 2];                                        \
    _Pragma("unroll")                                                         \
    for (int k_ = 0; k_ < K_SZ; ++k_) {                                       \
      const float dx_ = px_ - kps[3 * k_ + 0];                                \
      const float dy_ = py_ - kps[3 * k_ + 1];                                \
      const float dz_ = pz_ - kps[3 * k_ + 2];                                \
      const float d_ = sqrtf(fmaf(dx_, dx_, fmaf(dy_, dy_, dz_ * dz_)));      \
      wt[bufi][k_][tid] = fmaxf(1.0f - d_ * INV_KP_EXTENT, 0.0f);             \
    }                                                                         \
  } while (0)

#define DO_FMA_FB(xr, bufi)                                                   \
  do {                                                                        \
    _Pragma("unroll")                                                         \
    for (int k_ = 0; k_ < K_SZ; ++k_) {                                       \
      const float4 wq_ = *reinterpret_cast<const float4*>(&wt[bufi][k_][4 * lane]); \
      _Pragma("unroll")                                                       \
      for (int r_ = 0; r_ < ROWS; ++r_)                                       \
        acc[r_][k_] = fmaf(wq_.x, xr[r_].x,                                   \
                      fmaf(wq_.y, xr[r_].y,                                   \
                      fmaf(wq_.z, xr[r_].z,                                   \
                      fmaf(wq_.w, xr[r_].w, acc[r_][k_]))));                  \
    }                                                                         \
  } while (0)

  float4 xA[ROWS], xB[ROWS];
  __syncthreads();
  FILL_WT(0, 0);
  LOAD_X(xA, 0);
  __syncthreads();

  for (int t = 0; t < STEPS; t += 2) {
    if (t + 1 < STEPS) {
      LOAD_X(xB, t + 1);
      FILL_WT(1, t + 1);
    }
    DO_FMA_FB(xA, 0);
    __syncthreads();
    if (t + 1 < STEPS) {
      if (t + 2 < STEPS) {
        LOAD_X(xA, t + 2);
        FILL_WT(0, t + 2);
      }
      DO_FMA_FB(xB, 1);
      __syncthreads();
    }
  }

  float* pout = part + (size_t)blk * PART_PER_BLK + wid * (ROWS * K_SZ);
#pragma unroll
  for (int r = 0; r < ROWS; ++r) {
    float keep = 0.0f;
#pragma unroll
    for (int k = 0; k < K_SZ; ++k) {
      float v = acc[r][k];
      v += __shfl_xor(v, 1);
      v += __shfl_xor(v, 2);
      v += __shfl_xor(v, 4);
      v += __shfl_xor(v, 8);
      v += __shfl_xor(v, 16);
      v += __shfl_xor(v, 32);
      if (lane == k) keep = v;
    }
    if (lane < K_SZ) pout[r * K_SZ + lane] = keep;
  }
}

// part[blk][wid][r][k], blk = (b*G+cg)*S_SPANS + s, c = cg*16 + wid*4 + r.
__global__ __launch_bounds__(C_SZ) void kpconv_reduce_gemm(
    const float* __restrict__ part, const float* __restrict__ W,
    float* __restrict__ out) {
  const int k = blockIdx.x;
  const int b = blockIdx.y;
  const int tid = threadIdx.x;  // c
  __shared__ float row[C_SZ];

  const int cg = tid >> 4, wid = (tid >> 2) & 3, r = tid & 3;
  const size_t base = ((size_t)(b * G + cg) * S_SPANS) * PART_PER_BLK
                    + wid * (ROWS * K_SZ) + r * K_SZ + k;
  float sum = 0.0f;
  for (int ss = 0; ss < S_SPANS; ++ss)
    sum += part[base + (size_t)ss * PART_PER_BLK];
  row[tid] = sum;
  __syncthreads();

  float acc = 0.0f;
  const float* Wk = W + (size_t)k * C_SZ * C_SZ;
#pragma unroll 8
  for (int c = 0; c < C_SZ; ++c) acc += row[c] * Wk[(size_t)c * C_SZ + tid];
  atomicAdd(&out[b * C_SZ + tid], acc);
}

extern "C" void kernel_launch(void* const* d_in, const int* in_sizes, int n_in,
                              void* d_out, int out_size, void* d_ws, size_t ws_size,
                              hipStream_t stream) {
  const float* p  = (const float*)d_in[0];
  const float* x  = (const float*)d_in[1];
  const float* w  = (const float*)d_in[2];
  const float* kp = (const float*)d_in[3];
  float* out  = (float*)d_out;
  float* part = (float*)d_ws;

  const size_t part_bytes = (size_t)NBLKS * PART_PER_BLK * sizeof(float);  // ~1.97 MB
  const size_t walign = (part_bytes + 255) & ~(size_t)255;
  const size_t wbytes = (size_t)B_SZ * TILES * KPAD * NTILE * sizeof(float); // 33.55 MB

  (void)hipMemsetAsync(d_out, 0, (size_t)out_size * sizeof(float), stream);
  if (ws_size >= walign + wbytes) {
    float* wglob = (float*)((char*)d_ws + walign);
    kpconv_weights<<<dim3(B_SZ * TILES), THREADS, 0, stream>>>(p, kp, wglob);
    kpconv_main_pw<<<dim3(NBLKS), THREADS, 0, stream>>>(x, wglob, part);
  } else {
    kpconv_main_fb<<<dim3(NBLKS), THREADS, 0, stream>>>(p, x, kp, part);
  }
  kpconv_reduce_gemm<<<dim3(K_SZ, B_SZ), C_SZ, 0, stream>>>(part, w, out);
}